// Round 17
// baseline (16680.623 us; speedup 1.0000x reference)
//
#include <hip/hip_runtime.h>

#define NQ 12
#define NLAYERS 4

typedef float v2f __attribute__((ext_vector_type(2)));
typedef unsigned uint2v __attribute__((ext_vector_type(2)));

// ---- DPP move ----
template<int CTRL>
__device__ __forceinline__ float dppmov(float v) {
    return __uint_as_float((unsigned)__builtin_amdgcn_update_dpp(
        0, (int)__float_as_uint(v), CTRL, 0xF, 0xF, true));
}

// ---- value from lane ^ (1<<LB); DPP/permlane only ----
template<int LB>
__device__ __forceinline__ float lx(float v, int lane) {
    if constexpr (LB == 0) {
        return dppmov<0xB1>(v);                 // quad_perm xor1
    } else if constexpr (LB == 1) {
        return dppmov<0x4E>(v);                 // quad_perm xor2
    } else if constexpr (LB == 2) {
        float a = dppmov<0x124>(v);             // row_ror:4  -> reads (i-4)%16
        float b = dppmov<0x12C>(v);             // row_ror:12 -> reads (i+4)%16
        return (lane & 4) ? a : b;
    } else if constexpr (LB == 3) {
        return dppmov<0x128>(v);                // row_ror:8 = xor8
    } else if constexpr (LB == 4) {
#if __has_builtin(__builtin_amdgcn_permlane16_swap)
        uint2v r = __builtin_amdgcn_permlane16_swap(__float_as_uint(v), __float_as_uint(v), false, false);
        return __uint_as_float(r.x) + __uint_as_float(r.y) - v;
#else
        return __shfl_xor(v, 16, 64);
#endif
    } else {
#if __has_builtin(__builtin_amdgcn_permlane32_swap)
        uint2v r = __builtin_amdgcn_permlane32_swap(__float_as_uint(v), __float_as_uint(v), false, false);
        return __uint_as_float(r.x) + __uint_as_float(r.y) - v;
#else
        return __shfl_xor(v, 32, 64);
#endif
    }
}

template<int LB>
__device__ __forceinline__ v2f lxv(v2f a, int lane) {
    v2f r;
    r.x = lx<LB>(a.x, lane);
    r.y = lx<LB>(a.y, lane);
    return r;
}

// ======== ring permutation source map (XOR-linear) ========
template<int S>
__host__ __device__ constexpr int ringsrc_c(int k) {
    int s = k;
    for (int i = 11; i >= 0; --i) {
        const int pc = 11 - i;
        const int pt = 11 - ((i + S) % 12);
        s ^= ((s >> pc) & 1) << pt;
    }
    return s;
}

__host__ __device__ constexpr int rot3(int v, int J) {
    return J == 0 ? v : (((v << J) | (v >> (3 - J))) & 7);
}

// per-ring swizzle: phys_S(k) = k ^ rot3((k>>4)&7, J_S), J chosen by constexpr
// bank-pair spread scoring of the READ pattern (write side is rank-4 for any J).
template<int S>
__host__ __device__ constexpr int pickJ() {
    int best = 0, bestc = 0;
    for (int J = 0; J < 3; ++J) {
        bool seen[16] = {};
        int cnt = 0;
        for (int ln = 0; ln < 64; ++ln) {
            int k = ln << 3;
            int s = ringsrc_c<S>(k);
            int p = (s ^ rot3((s >> 4) & 7, J)) & 15;
            if (!seen[p]) { seen[p] = true; ++cnt; }
        }
        if (cnt > bestc) { bestc = cnt; best = J; }
    }
    return best;
}
template<int S>
__host__ __device__ constexpr int phys_s(int k) {
    return k ^ rot3((k >> 4) & 7, pickJ<S>());
}

struct LUT8 { int v[8]; };
template<int S>
__host__ __device__ constexpr LUT8 make_lr8() {
    LUT8 a{};
    for (int r = 0; r < 8; ++r) a.v[r] = ringsrc_c<S>(r);
    return a;
}
template<int S>
__host__ __device__ constexpr LUT8 make_pr8() {
    LUT8 a{};
    for (int r = 0; r < 8; ++r) a.v[r] = phys_s<S>(ringsrc_c<S>(r));
    return a;
}
template<int S>
__host__ __device__ constexpr bool grp_used8(int h) {
    for (int r = 0; r < 8; ++r)
        if (((ringsrc_c<S>(r) >> 9) & 7) == h) return true;
    return false;
}

// ================= real RY gates =================
template<int RB>
__device__ __forceinline__ void ry_reg(v2f (&st)[8], float c, float s) {
    #pragma unroll
    for (int r = 0; r < 8; ++r) if (!(r & (1 << RB))) {
        const int r1 = r | (1 << RB);
        v2f a0 = st[r], a1 = st[r1];
        st[r]  = c * a0 - s * a1;
        st[r1] = s * a0 + c * a1;
    }
}
template<int LB>
__device__ __forceinline__ void ry_lane(v2f (&st)[8], int lane, float c, float s) {
    const float so = ((lane >> LB) & 1) ? s : -s;
    #pragma unroll
    for (int r = 0; r < 8; ++r) {
        v2f oth = lxv<LB>(st[r], lane);
        st[r] = c * st[r] + so * oth;
    }
}

// ================= diagonal: st[r] *= e^{i(A + sum_{bits b of r} angle_b)} =========
// f = 3 (cos,sin) pairs: f[b] = e^{i*angle} for r-bit b (b=0 -> wire11, 1 -> w10, 2 -> w9)
__device__ __forceinline__ void diag_apply8(v2f (&st)[8], float A, const float* __restrict__ f) {
    float sA, cA;
    __sincosf(A, &sA, &cA);
    v2f p[8];
    p[0] = v2f{cA, sA};
    #pragma unroll
    for (int r = 1; r < 8; ++r) {
        const int b = (r & 1) ? 0 : ((r & 2) ? 1 : 2);
        const v2f q = p[r & (r - 1)];
        const float fc = f[2 * b], fs = f[2 * b + 1];
        p[r] = v2f{fc * q.x - fs * q.y, fc * q.y + fs * q.x};
    }
    #pragma unroll
    for (int r = 0; r < 8; ++r) {
        const v2f a = st[r], q = p[r];
        st[r] = v2f{a.x * q.x - a.y * q.y, a.x * q.y + a.y * q.x};
    }
}

// ================= fused trip: RY(w0)⊗RY(w1)⊗RY(w2) [+row phases] + ring-S =========
template<int S, int H, bool RP>
__device__ __forceinline__ void trip_group(v2f (&st)[8], int pb, int rowbase,
                                           const v2f* buf, const float* __restrict__ P) {
    if constexpr (grp_used8<S>(H)) {
        const int row = rowbase ^ H;
        const float* R = P + 64 + row * 8;
        const float m0 = R[0], m1 = R[1], m2 = R[2], m3 = R[3],
                    m4 = R[4], m5 = R[5], m6 = R[6], m7 = R[7];
        float pc = 0.f, ps = 0.f;
        if constexpr (RP) { pc = P[128 + 2 * row]; ps = P[129 + 2 * row]; }
        constexpr LUT8 LR = make_lr8<S>();
        constexpr LUT8 PR = make_pr8<S>();
        #pragma unroll
        for (int r = 0; r < 8; ++r) {
            if (((LR.v[r] >> 9) & 7) == H) {           // constant-folded
                const int a = (pb ^ PR.v[r]) & 511;     // strip wave bits
                v2f acc = m0 * buf[a]
                        + m1 * buf[a + 512]
                        + m2 * buf[a + 1024]
                        + m3 * buf[a + 1536]
                        + m4 * buf[a + 2048]
                        + m5 * buf[a + 2560]
                        + m6 * buf[a + 3072]
                        + m7 * buf[a + 3584];
                if constexpr (RP)
                    st[r] = v2f{acc.x * pc - acc.y * ps, acc.y * pc + acc.x * ps};
                else
                    st[r] = acc;
            }
        }
    }
}

// ================= one layer: D_phi -> 9 RY -> [D_om(3..11)] -> fused trip ==========
// P layout (stride 160): [0..11] c  [12..23] s  [24..35] phi/2  [36..47] om/2
// [48..53] fphi pairs (wires 11,10,9)  [54..59] fom pairs  [60] -sum(phi/2)
// [61] -sum_{w>=3}(om/2)  [64..127] M8[8][8]  [128..143] row phases (cos,sin)
template<int S, bool FULL>
__device__ __forceinline__ void do_layer(v2f (&st)[8], int lane, int wv, int wbase,
                                         v2f* xch, const float* __restrict__ P) {
    {   // D_phi (all 12 wires)
        float A = P[60];
        A += ((wv >> 2) & 1) ? 2.f * P[24 + 0] : 0.f;
        A += ((wv >> 1) & 1) ? 2.f * P[24 + 1] : 0.f;
        A += (wv & 1)        ? 2.f * P[24 + 2] : 0.f;
        #pragma unroll
        for (int w = 3; w < 9; ++w)
            A += ((lane >> (8 - w)) & 1) ? 2.f * P[24 + w] : 0.f;
        diag_apply8(st, A, P + 48);
    }
    ry_lane<5>(st, lane, P[3],  P[15]);   // wire 3
    ry_lane<4>(st, lane, P[4],  P[16]);   // wire 4
    ry_lane<3>(st, lane, P[5],  P[17]);   // wire 5
    ry_lane<2>(st, lane, P[6],  P[18]);   // wire 6
    ry_lane<1>(st, lane, P[7],  P[19]);   // wire 7
    ry_lane<0>(st, lane, P[8],  P[20]);   // wire 8
    ry_reg<2>(st, P[9],  P[21]);          // wire 9
    ry_reg<1>(st, P[10], P[22]);          // wire 10
    ry_reg<0>(st, P[11], P[23]);          // wire 11
    if constexpr (FULL) {   // D_om wires 3..11 (wires 0-2's omega in trip row phases)
        float A = P[61];
        #pragma unroll
        for (int w = 3; w < 9; ++w)
            A += ((lane >> (8 - w)) & 1) ? 2.f * P[36 + w] : 0.f;
        diag_apply8(st, A, P + 54);
    }
    // trip: write phys_S(k) (phys linear; phys(r)=r for r<8)
    const int pw = wbase ^ rot3((wbase >> 4) & 7, pickJ<S>());
    #pragma unroll
    for (int r = 0; r < 8; ++r) xch[pw ^ r] = st[r];
    __syncthreads();
    const int sb = ringsrc_c<S>(wbase);
    const int pb = sb ^ rot3((sb >> 4) & 7, pickJ<S>());
    const int rowbase = (sb >> 9) & 7;
    trip_group<S, 0, FULL>(st, pb, rowbase, xch, P);
    trip_group<S, 1, FULL>(st, pb, rowbase, xch, P);
    trip_group<S, 2, FULL>(st, pb, rowbase, xch, P);
    trip_group<S, 3, FULL>(st, pb, rowbase, xch, P);
    trip_group<S, 4, FULL>(st, pb, rowbase, xch, P);
    trip_group<S, 5, FULL>(st, pb, rowbase, xch, P);
    trip_group<S, 6, FULL>(st, pb, rowbase, xch, P);
    trip_group<S, 7, FULL>(st, pb, rowbase, xch, P);
    __syncthreads();
}

// ================= param precompute =================
__global__ void prep_mats(const float* __restrict__ w3, float* __restrict__ prm) {
    int t = threadIdx.x;
    if (t < NLAYERS * NQ) {
        int l = t / 12, w = t % 12;
        float phi = w3[t * 3 + 0], th = w3[t * 3 + 1], om = w3[t * 3 + 2];
        float* P = prm + l * 160;
        P[w]      = cosf(0.5f * th);
        P[12 + w] = sinf(0.5f * th);
        P[24 + w] = 0.5f * phi;
        P[36 + w] = 0.5f * om;
    }
    if (t < NLAYERS) {
        const int l = t;
        const float* W = w3 + l * 36;
        float* P = prm + l * 160;
        float nphi = 0.f, nomg = 0.f;
        for (int w = 0; w < 12; ++w) nphi -= 0.5f * W[w * 3 + 0];
        for (int w = 3; w < 12; ++w) nomg -= 0.5f * W[w * 3 + 2];
        P[60] = nphi;
        P[61] = nomg;
        for (int b = 0; b < 3; ++b) {
            int w = 11 - b;
            P[48 + 2 * b] = cosf(W[w * 3 + 0]);  P[49 + 2 * b] = sinf(W[w * 3 + 0]);
            P[54 + 2 * b] = cosf(W[w * 3 + 2]);  P[55 + 2 * b] = sinf(W[w * 3 + 2]);
        }
        float R[3][2][2];
        float ho[3];
        for (int q = 0; q < 3; ++q) {
            float c = cosf(0.5f * W[q * 3 + 1]), s = sinf(0.5f * W[q * 3 + 1]);
            R[q][0][0] = c;  R[q][0][1] = -s;
            R[q][1][0] = s;  R[q][1][1] = c;
            ho[q] = 0.5f * W[q * 3 + 2];
        }
        for (int i = 0; i < 8; ++i) {
            for (int j = 0; j < 8; ++j)
                P[64 + i * 8 + j] = R[0][i >> 2][j >> 2] *
                                    R[1][(i >> 1) & 1][(j >> 1) & 1] *
                                    R[2][i & 1][j & 1];
            float beta = (2 * (i >> 2) - 1) * ho[0] +
                         (2 * ((i >> 1) & 1) - 1) * ho[1] +
                         (2 * (i & 1) - 1) * ho[2];
            P[128 + 2 * i] = cosf(beta);
            P[129 + 2 * i] = sinf(beta);
        }
    }
}

__device__ __forceinline__ float wsum(float v, int lane) {
    v += lx<5>(v, lane); v += lx<4>(v, lane); v += lx<3>(v, lane);
    v += lx<2>(v, lane); v += lx<1>(v, lane); v += lx<0>(v, lane);
    return v;
}

// ================= main kernel: 512 threads (8 waves), 8 amps/lane =================
// waves_per_eu(2,8): the backend computes the VGPR budget as 256/min_waves —
// (8)->32 VGPR (R15, 2GB spill), (4,8)->64 (R16, 1.4GB spill). min=2 gives a
// 128-VGPR budget (the R4-proven no-spill config); max=8 still lets the
// allocator reach <=64 for full residency if the working set allows.
__global__ __launch_bounds__(512)
__attribute__((amdgpu_waves_per_eu(2, 8)))
void qsim_kernel(
    const float* __restrict__ x,       // [B][NQ]
    const float* __restrict__ prm,     // 4 x 160 floats
    float* __restrict__ out)           // [B][NQ]
{
    __shared__ v2f xch[4096];          // 32 KB shared by 8 waves

    const int b     = blockIdx.x;
    const int tid   = threadIdx.x;
    const int wv    = tid >> 6;        // 3 wave bits = wires 0,1,2 (k bits 11,10,9)
    const int lane  = tid & 63;        // 6 lane bits = wires 3..8 (k bits 8..3)
    const int wbase = (wv << 9) | (lane << 3);

    const float PI = 3.14159265358979323846f;

    // ---- RY product state with initial ring1 folded in (zero LDS) ----
    float cs[12], sn[12];
    #pragma unroll
    for (int w = 0; w < 12; ++w) {
        float h = 0.5f * PI * x[b * NQ + w];
        __sincosf(h, &sn[w], &cs[w]);
    }
    const int sbi = ringsrc_c<1>(wbase);
    float LF = 1.f;
    #pragma unroll
    for (int w = 2; w < 9; ++w)
        LF *= ((sbi >> (11 - w)) & 1) ? sn[w] : cs[w];
    constexpr LUT8 L1R = make_lr8<1>();
    v2f st[8];
    #pragma unroll
    for (int r = 0; r < 8; ++r) {
        const int idx = sbi ^ L1R.v[r];
        float f = LF;
        f *= ((idx >> 11) & 1) ? sn[0]  : cs[0];
        f *= ((idx >> 10) & 1) ? sn[1]  : cs[1];
        f *= ((idx >> 2) & 1)  ? sn[9]  : cs[9];
        f *= ((idx >> 1) & 1)  ? sn[10] : cs[10];
        f *= ( idx       & 1)  ? sn[11] : cs[11];
        st[r] = v2f{f, 0.f};
    }

    // ---- 4 entangling layers (last: drop |.|^2-invariant phases) ----
    do_layer<1, true >(st, lane, wv, wbase, xch, prm + 0);
    do_layer<2, true >(st, lane, wv, wbase, xch, prm + 160);
    do_layer<3, true >(st, lane, wv, wbase, xch, prm + 320);
    do_layer<4, false>(st, lane, wv, wbase, xch, prm + 480);

    // ---- per-wire <Z> ----
    float S = 0.f;
    float aR[3] = {0.f, 0.f, 0.f};
    #pragma unroll
    for (int r = 0; r < 8; ++r) {
        v2f sq = st[r] * st[r];
        float pr = sq.x + sq.y;
        S += pr;
        #pragma unroll
        for (int rb = 0; rb < 3; ++rb)
            aR[rb] += ((r >> rb) & 1) ? -pr : pr;
    }

    float* red = (float*)xch;          // [8][12]

    {   // wave wires 0,1,2: one butterfly, wave-dependent sign at write
        float T = wsum(S, lane);
        if (lane == 0) {
            red[wv * 12 + 0] = ((wv >> 2) & 1) ? -T : T;
            red[wv * 12 + 1] = ((wv >> 1) & 1) ? -T : T;
            red[wv * 12 + 2] = (wv & 1)        ? -T : T;
        }
    }
    #pragma unroll
    for (int W = 3; W < 9; ++W) {      // lane wires
        float v0 = ((lane >> (8 - W)) & 1) ? -S : S;
        v0 = wsum(v0, lane);
        if (lane == 0) red[wv * 12 + W] = v0;
    }
    #pragma unroll
    for (int W = 9; W < 12; ++W) {     // reg wires
        float v0 = wsum(aR[11 - W], lane);
        if (lane == 0) red[wv * 12 + W] = v0;
    }
    __syncthreads();
    if (tid < 12) {
        float s = 0.f;
        #pragma unroll
        for (int w8 = 0; w8 < 8; ++w8) s += red[w8 * 12 + tid];
        out[b * NQ + tid] = s;
    }
}

extern "C" void kernel_launch(void* const* d_in, const int* in_sizes, int n_in,
                              void* d_out, int out_size, void* d_ws, size_t ws_size,
                              hipStream_t stream) {
    const float* x  = (const float*)d_in[0];   // [B][NQ] float32
    const float* w3 = (const float*)d_in[1];   // [NLAYERS][NQ][3] float32
    float* out = (float*)d_out;                // [B][NQ] float32
    float* prm = (float*)d_ws;                 // 4*160 floats = 2.5 KB
    int batch = in_sizes[0] / NQ;
    prep_mats<<<1, 64, 0, stream>>>(w3, prm);
    qsim_kernel<<<batch, 512, 0, stream>>>(x, prm, out);
}

// Round 18
// 58.795 us; speedup vs baseline: 283.7086x; 283.7086x over previous
//
#include <hip/hip_runtime.h>

#define NQ 12
#define NLAYERS 4

typedef float v2f __attribute__((ext_vector_type(2)));
typedef unsigned uint2v __attribute__((ext_vector_type(2)));

// ---- DPP move: value from another lane, compile-time ctrl ----
template<int CTRL>
__device__ __forceinline__ float dppmov(float v) {
    return __uint_as_float((unsigned)__builtin_amdgcn_update_dpp(
        0, (int)__float_as_uint(v), CTRL, 0xF, 0xF, true));
}

// ---- value from lane ^ (1<<LB); all 64 lanes active; NO DS-pipe ops ----
// DPP row_ror:n semantics: lane i reads lane (i-n) mod 16.
template<int LB>
__device__ __forceinline__ float lx(float v, int lane) {
    if constexpr (LB == 0) {
        return dppmov<0xB1>(v);                 // quad_perm [1,0,3,2] = xor1
    } else if constexpr (LB == 1) {
        return dppmov<0x4E>(v);                 // quad_perm [2,3,0,1] = xor2
    } else if constexpr (LB == 2) {
        float a = dppmov<0x124>(v);             // row_ror:4  -> reads (i-4)%16
        float b = dppmov<0x12C>(v);             // row_ror:12 -> reads (i+4)%16
        return (lane & 4) ? a : b;              // bit2=1 needs i-4 ; bit2=0 needs i+4
    } else if constexpr (LB == 3) {
        return dppmov<0x128>(v);                // row_ror:8 = xor8 (direction-symmetric)
    } else if constexpr (LB == 4) {
#if __has_builtin(__builtin_amdgcn_permlane16_swap)
        uint2v r = __builtin_amdgcn_permlane16_swap(__float_as_uint(v), __float_as_uint(v), false, false);
        return __uint_as_float(r.x) + __uint_as_float(r.y) - v;   // partner
#else
        return __shfl_xor(v, 16, 64);
#endif
    } else {
#if __has_builtin(__builtin_amdgcn_permlane32_swap)
        uint2v r = __builtin_amdgcn_permlane32_swap(__float_as_uint(v), __float_as_uint(v), false, false);
        return __uint_as_float(r.x) + __uint_as_float(r.y) - v;
#else
        return __shfl_xor(v, 32, 64);
#endif
    }
}

template<int LB>
__device__ __forceinline__ v2f lxv(v2f a, int lane) {
    v2f r;
    r.x = lx<LB>(a.x, lane);
    r.y = lx<LB>(a.y, lane);
    return r;
}

__device__ __forceinline__ v2f swap2(v2f a) { return __builtin_shufflevector(a, a, 1, 0); }

// ======== composed ring permutation: source index for CNOT ring (i,(i+S)%12), i=0..11 ========
// state'[k] = state[C0(C1(...C11(k)))]  (wire w <-> bit 11-w); XOR-linear in k.
template<int S>
__host__ __device__ constexpr int ringsrc_c(int k) {
    int s = k;
    for (int i = 11; i >= 0; --i) {
        const int pc = 11 - i;
        const int pt = 11 - ((i + S) % 12);
        s ^= ((s >> pc) & 1) << pt;
    }
    return s;
}

// rotate-right-1 on a 4-bit value
__host__ __device__ constexpr int ror1_4(int m) {
    return ((m >> 1) | ((m & 1) << 3)) & 15;
}
// LDS swizzle (GF(2)-linear): phys(s) = s ^ ror1(mid4). Rank-4 lane-spread for
// the write AND for the ring-S reads, S=1..4 (S=4 was rank-2 with the old mid4
// swizzle -> 32-way conflicts). Bits 10,11 untouched.
__host__ __device__ constexpr int phys_lin(int s) {
    return s ^ ror1_4((s >> 4) & 15);
}

struct LUT16 { int v[16]; };

template<int S>
__host__ __device__ constexpr LUT16 make_lr() {
    LUT16 a{};
    for (int r = 0; r < 16; ++r) a.v[r] = ringsrc_c<S>(r);
    return a;
}
template<int S>
__host__ __device__ constexpr LUT16 make_pr() {
    LUT16 a{};
    for (int r = 0; r < 16; ++r) a.v[r] = phys_lin(ringsrc_c<S>(r));
    return a;
}

template<int S>
__host__ __device__ constexpr bool grp_used(int h) {
    for (int r = 0; r < 16; ++r)
        if (((ringsrc_c<S>(r) >> 10) & 3) == h) return true;
    return false;
}

// M (per-wire) layout: [m00xx,m00yy, m01xx,m01yy, m10xx,m10yy, m11xx,m11yy]
// mxx = {m.x,m.x}, myy = {-m.y,m.y};  m*a = mxx*a + myy*swap2(a)  (2x v_pk_fma_f32)

// ================= in-register Rot gates (wires 2..11) =================
template<int RB>
__device__ __forceinline__ void gate_reg(v2f (&st)[16], const v2f* __restrict__ M) {
    const v2f m00xx = M[0], m00yy = M[1], m01xx = M[2], m01yy = M[3];
    const v2f m10xx = M[4], m10yy = M[5], m11xx = M[6], m11yy = M[7];
    #pragma unroll
    for (int r = 0; r < 16; ++r) if (!(r & (1 << RB))) {
        const int r1 = r | (1 << RB);
        v2f a0 = st[r], a1 = st[r1];
        st[r]  = m00xx * a0 + m00yy * swap2(a0) + m01xx * a1 + m01yy * swap2(a1);
        st[r1] = m10xx * a0 + m10yy * swap2(a0) + m11xx * a1 + m11yy * swap2(a1);
    }
}

template<int LB>
__device__ __forceinline__ void gate_lane(v2f (&st)[16], int lane, const v2f* __restrict__ M) {
    const bool hi = (lane >> LB) & 1;
    const v2f mSxx = hi ? M[6] : M[0], mSyy = hi ? M[7] : M[1];
    const v2f mOxx = hi ? M[4] : M[2], mOyy = hi ? M[5] : M[3];
    #pragma unroll
    for (int r = 0; r < 16; ++r) {
        v2f own = st[r];
        v2f oth = lxv<LB>(own, lane);
        st[r] = mSxx * own + mSyy * swap2(own) + mOxx * oth + mOyy * swap2(oth);
    }
}

// ================= fused trip: Rot(wire0)⊗Rot(wire1) + ring-S, ONE LDS round trip =================
// C = Rot01(A); B[k] = C[L(k)] = sum_{w'} M4[wb(L(k))][w'] * A[L(k) with wavebits=w'].
template<int S, int H>
__device__ __forceinline__ void trip_group(v2f (&st)[16], int pb, int rowbase,
                                           const v2f* xch, const v2f* m4) {
    if constexpr (grp_used<S>(H)) {
        const int row = rowbase ^ H;
        v2f mxx[4], myy[4];
        #pragma unroll
        for (int j = 0; j < 4; ++j) {
            mxx[j] = m4[(row * 4 + j) * 2 + 0];
            myy[j] = m4[(row * 4 + j) * 2 + 1];
        }
        constexpr LUT16 LR = make_lr<S>();
        constexpr LUT16 PR = make_pr<S>();
        #pragma unroll
        for (int r = 0; r < 16; ++r) {
            if (((LR.v[r] >> 10) & 3) == H) {          // constant-folded per unrolled r
                const int a = (pb ^ PR.v[r]) & 1023;    // phys addr, wave bits stripped
                v2f o0 = xch[a];
                v2f o1 = xch[a + 1024];
                v2f o2 = xch[a + 2048];
                v2f o3 = xch[a + 3072];
                st[r] = mxx[0] * o0 + myy[0] * swap2(o0)
                      + mxx[1] * o1 + myy[1] * swap2(o1)
                      + mxx[2] * o2 + myy[2] * swap2(o2)
                      + mxx[3] * o3 + myy[3] * swap2(o3);
            }
        }
    }
}

template<int S>
__device__ __forceinline__ void fused_trip(v2f (&st)[16], int wbase, int lsw,
                                           v2f* xch, const v2f* m4) {
    #pragma unroll
    for (int r = 0; r < 16; ++r) xch[wbase | (r ^ lsw)] = st[r];
    __syncthreads();
    const int sb = ringsrc_c<S>(wbase);
    const int pb = phys_lin(sb);
    const int rowbase = (sb >> 10) & 3;
    trip_group<S, 0>(st, pb, rowbase, xch, m4);
    trip_group<S, 1>(st, pb, rowbase, xch, m4);
    trip_group<S, 2>(st, pb, rowbase, xch, m4);
    trip_group<S, 3>(st, pb, rowbase, xch, m4);
    __syncthreads();
}

// ================= one entangling layer: 10 in-register Rots + fused trip =================
template<int S>
__device__ __forceinline__ void do_layer(v2f (&st)[16], int lane, int wbase, int lsw,
                                         v2f* xch, const v2f* m4,
                                         const v2f* __restrict__ Mw) {
    gate_lane<5>(st, lane, Mw + 2 * 8);   // wire 2  (xor32, permlane32)
    gate_lane<4>(st, lane, Mw + 3 * 8);   // wire 3  (xor16, permlane16)
    gate_lane<3>(st, lane, Mw + 4 * 8);   // wire 4  (xor8, DPP ror:8)
    gate_lane<2>(st, lane, Mw + 5 * 8);   // wire 5  (xor4, DPP ror4/12)
    gate_lane<1>(st, lane, Mw + 6 * 8);   // wire 6  (xor2, DPP)
    gate_lane<0>(st, lane, Mw + 7 * 8);   // wire 7  (xor1, DPP)
    gate_reg<3>(st, Mw + 8 * 8);          // wire 8
    gate_reg<2>(st, Mw + 9 * 8);          // wire 9
    gate_reg<1>(st, Mw + 10 * 8);         // wire 10
    gate_reg<0>(st, Mw + 11 * 8);         // wire 11
    fused_trip<S>(st, wbase, lsw, xch, m4);   // Rot(w0)⊗Rot(w1) + ring S
}

// ================= matrix precompute (batch-independent, packed) =================
// mats layout: [l][w][8] v2f for w=0..11 (l*96 + w*8), then M4 blocks at 384 + l*32.
__global__ void prep_mats(const float* __restrict__ w3, v2f* __restrict__ mats) {
    int t = threadIdx.x;
    if (t < NLAYERS * NQ) {
        float phi = w3[t * 3 + 0], th = w3[t * 3 + 1], om = w3[t * 3 + 2];
        float ct = cosf(0.5f * th), s = sinf(0.5f * th);
        float ap = 0.5f * (phi + om), am = 0.5f * (phi - om);
        float cap = cosf(ap), sap = sinf(ap);
        float cam = cosf(am), sam = sinf(am);
        float2 m00 = make_float2( cap * ct, -sap * ct);
        float2 m01 = make_float2(-cam * s,  -sam * s);
        float2 m10 = make_float2( cam * s,  -sam * s);
        float2 m11 = make_float2( cap * ct,  sap * ct);
        v2f* M = mats + t * 8;
        M[0] = v2f{m00.x, m00.x};  M[1] = v2f{-m00.y, m00.y};
        M[2] = v2f{m01.x, m01.x};  M[3] = v2f{-m01.y, m01.y};
        M[4] = v2f{m10.x, m10.x};  M[5] = v2f{-m10.y, m10.y};
        M[6] = v2f{m11.x, m11.x};  M[7] = v2f{-m11.y, m11.y};
    }
    if (t < NLAYERS) {
        const int l = t;
        float2 mm[2][2][2];   // [wire][row][col] complex
        for (int w = 0; w < 2; ++w) {
            float phi = w3[(l * NQ + w) * 3 + 0], th = w3[(l * NQ + w) * 3 + 1],
                  om  = w3[(l * NQ + w) * 3 + 2];
            float ct = cosf(0.5f * th), s = sinf(0.5f * th);
            float ap = 0.5f * (phi + om), am = 0.5f * (phi - om);
            float cap = cosf(ap), sap = sinf(ap);
            float cam = cosf(am), sam = sinf(am);
            mm[w][0][0] = make_float2( cap * ct, -sap * ct);
            mm[w][0][1] = make_float2(-cam * s,  -sam * s);
            mm[w][1][0] = make_float2( cam * s,  -sam * s);
            mm[w][1][1] = make_float2( cap * ct,  sap * ct);
        }
        // M4[i][j] = M_wire0[i>>1][j>>1] * M_wire1[i&1][j&1]; i = 2*bit11 + bit10
        v2f* M4 = mats + NLAYERS * 96 + l * 32;
        for (int i = 0; i < 4; ++i)
            for (int j = 0; j < 4; ++j) {
                float2 a = mm[0][i >> 1][j >> 1];
                float2 bq = mm[1][i & 1][j & 1];
                float2 pq = make_float2(a.x * bq.x - a.y * bq.y, a.x * bq.y + a.y * bq.x);
                M4[(i * 4 + j) * 2 + 0] = v2f{pq.x, pq.x};
                M4[(i * 4 + j) * 2 + 1] = v2f{-pq.y, pq.y};
            }
    }
}

__device__ __forceinline__ float wsum(float v, int lane) {
    v += lx<5>(v, lane); v += lx<4>(v, lane); v += lx<3>(v, lane);
    v += lx<2>(v, lane); v += lx<1>(v, lane); v += lx<0>(v, lane);
    return v;
}

// ================= main kernel =================
__global__ __launch_bounds__(256)
__attribute__((amdgpu_waves_per_eu(2, 4)))
void qsim_kernel(
    const float* __restrict__ x,       // [B][NQ]
    const v2f* __restrict__ mats,      // packed per-wire mats + M4 blocks
    float* __restrict__ out)           // [B][NQ]
{
    __shared__ v2f xch[4096];               // 32 KB state exchange (phys-swizzled)
    __shared__ v2f m4l[NLAYERS * 32];       // 1 KB: per-layer 4x4 wave-gate

    const int b     = blockIdx.x;
    const int tid   = threadIdx.x;
    const int wv    = tid >> 6;
    const int lane  = tid & 63;
    const int wbase = (wv << 10) | (lane << 4);
    const int lsw   = ror1_4(lane & 15);

    if (tid < NLAYERS * 32) m4l[tid] = mats[NLAYERS * 96 + tid];  // covered by 1st trip barrier

    const float PI = 3.14159265358979323846f;

    // ---- RY product state WITH initial ring1 folded in (zero LDS):
    // st[r] = amp[ringsrc1(wbase|r)], amp(k) = prod_w (bit_{11-w}(k) ? sin_w : cos_w)
    float cs[12], sn[12];
    #pragma unroll
    for (int w = 0; w < 12; ++w) {
        float h = 0.5f * PI * x[b * NQ + w];
        __sincosf(h, &sn[w], &cs[w]);
    }
    const int sbi = ringsrc_c<1>(wbase);
    float LF = 1.f;
    #pragma unroll
    for (int w = 2; w < 8; ++w)                       // bits 9..4 are r-independent for S=1
        LF *= ((sbi >> (11 - w)) & 1) ? sn[w] : cs[w];
    constexpr LUT16 L1R = make_lr<1>();
    v2f st[16];
    #pragma unroll
    for (int r = 0; r < 16; ++r) {
        const int idx = sbi ^ L1R.v[r];
        float f = LF;
        f *= ((idx >> 11) & 1) ? sn[0]  : cs[0];
        f *= ((idx >> 10) & 1) ? sn[1]  : cs[1];
        f *= ((idx >> 3) & 1)  ? sn[8]  : cs[8];
        f *= ((idx >> 2) & 1)  ? sn[9]  : cs[9];
        f *= ((idx >> 1) & 1)  ? sn[10] : cs[10];
        f *= ( idx       & 1)  ? sn[11] : cs[11];
        st[r] = v2f{f, 0.f};
    }

    // ---- 4 entangling layers: 10 in-reg Rots + ONE fused (Rot01 + ring) trip each ----
    do_layer<1>(st, lane, wbase, lsw, xch, m4l + 0,   mats + 0);
    do_layer<2>(st, lane, wbase, lsw, xch, m4l + 32,  mats + 96);
    do_layer<3>(st, lane, wbase, lsw, xch, m4l + 64,  mats + 192);
    do_layer<4>(st, lane, wbase, lsw, xch, m4l + 96,  mats + 288);

    // ---- per-wire <Z> ----
    float S = 0.f;
    float aR[4] = {0.f, 0.f, 0.f, 0.f};
    #pragma unroll
    for (int r = 0; r < 16; ++r) {
        v2f sq = st[r] * st[r];
        float pr = sq.x + sq.y;
        S += pr;
        #pragma unroll
        for (int rb = 0; rb < 4; ++rb)
            aR[rb] += ((r >> rb) & 1) ? -pr : pr;
    }

    float* red = (float*)xch;

    {   // wave wires 0,1: one butterfly, wave-dependent sign at write
        float T = wsum(S, lane);
        if (lane == 0) {
            red[wv * 12 + 0] = ((wv >> 1) & 1) ? -T : T;
            red[wv * 12 + 1] = (wv & 1) ? -T : T;
        }
    }
    #pragma unroll
    for (int W = 2; W < 8; ++W) {      // lane wires
        float v0 = ((lane >> (7 - W)) & 1) ? -S : S;
        v0 = wsum(v0, lane);
        if (lane == 0) red[wv * 12 + W] = v0;
    }
    #pragma unroll
    for (int W = 8; W < 12; ++W) {     // reg wires
        float v0 = wsum(aR[11 - W], lane);
        if (lane == 0) red[wv * 12 + W] = v0;
    }
    __syncthreads();
    if (tid < 12)
        out[b * NQ + tid] = red[tid] + red[12 + tid] + red[24 + tid] + red[36 + tid];
}

extern "C" void kernel_launch(void* const* d_in, const int* in_sizes, int n_in,
                              void* d_out, int out_size, void* d_ws, size_t ws_size,
                              hipStream_t stream) {
    const float* x  = (const float*)d_in[0];   // [B][NQ] float32
    const float* w3 = (const float*)d_in[1];   // [NLAYERS][NQ][3] float32
    float* out = (float*)d_out;                // [B][NQ] float32
    v2f* mats = (v2f*)d_ws;                    // (4*96 + 4*32) * 8 B = 4 KB
    int batch = in_sizes[0] / NQ;
    prep_mats<<<1, 64, 0, stream>>>(w3, mats);
    qsim_kernel<<<batch, 256, 0, stream>>>(x, mats, out);
}